// Round 8
// baseline (233.970 us; speedup 1.0000x reference)
//
#include <hip/hip_runtime.h>
#include <math.h>

typedef float f32x4 __attribute__((ext_vector_type(4)));
typedef short s16x8 __attribute__((ext_vector_type(8)));
typedef unsigned int u32;
typedef unsigned short u16;
typedef u16 u16x4 __attribute__((ext_vector_type(4)));

// ---------------- ws layout (float offsets), 58.5 MB peak ----------------
// XQ region:   xq bf16 [16,512,1024] (prep..sim_gemm) -> vT bf16 [16,1024,512]
//              (conv..gemm2). Same size.
// ATTNT region: attnT bf16 [16,512,512] — OWN region (de-aliased, R7 insurance)
// SIMT region: simT bf16 [16,512,512] (sim..softmax_t) -> wattn bf16
//              [16,256,512] (gemm1..gemm2)
static constexpr size_t OFF_XT    = 0;          // bf16 [16,1156,512] = 4,734,976 fl
static constexpr size_t OFF_XQ    = 4734976;    // 4,194,304 fl
static constexpr size_t OFF_ATTNT = 8929280;    // 2,097,152 fl
static constexpr size_t OFF_SIMT  = 11026432;   // 2,097,152 fl
static constexpr size_t OFF_WA    = 13123584;   // bf16 [512,4608] = 1,179,648 fl
static constexpr size_t OFF_RM    = 14303232;   // f32 [512,512] = 262,144 fl
static constexpr size_t OFF_WWB   = 14565376;   // bf16 [256,512] = 65,536 fl
// end 14,630,912 fl = 58.5 MB (< 59.77 MB proven in R1)

__device__ __forceinline__ u16 f2bf(float f) {
    u32 u = __float_as_uint(f);
    u32 r = (u + 0x7FFFu + ((u >> 16) & 1u)) >> 16;   // RNE
    return (u16)r;
}
__device__ __forceinline__ float bf2f(u16 v) {
    return __uint_as_float(((u32)v) << 16);
}

__device__ __forceinline__ void gload_lds16(const void* g, void* l) {
    __builtin_amdgcn_global_load_lds(
        (const u32 __attribute__((address_space(1)))*)(uintptr_t)g,
        (u32 __attribute__((address_space(3)))*)(uintptr_t)l, 16, 0, 0);
}

// ================================================================ PREP (R6-proven)
__global__ __launch_bounds__(256) void prep_kernel(const float* __restrict__ x1,
                                                   const float* __restrict__ x2,
                                                   const float* __restrict__ gw,
                                                   const float* __restrict__ ww,
                                                   const float* __restrict__ w1,
                                                   const float* __restrict__ w2,
                                                   float* __restrict__ rm,
                                                   u16* __restrict__ wA,
                                                   u16* __restrict__ wwb,
                                                   u16* __restrict__ xT,
                                                   u16* __restrict__ xq) {
    __shared__ __attribute__((aligned(16))) u32 shm[4608];
    const int t = threadIdx.x;
    const int bid = blockIdx.x;

    if (bid < 512) {                        // ---- gw permute-cast
        const int co = bid;
        const float* g = gw + (size_t)co * 4608;
        float* lf = (float*)shm;
#pragma unroll
        for (int i = 0; i < 18; ++i) lf[t + i * 256] = g[t + i * 256];
        __syncthreads();
        u16* dst = wA + (size_t)co * 4608;
#pragma unroll
        for (int i = 0; i < 18; ++i) {
            int k = t + i * 256;
            int r = k >> 9, ci = k & 511;
            dst[k] = f2bf(lf[ci * 9 + r]);
        }
    } else if (bid < 2560) {                // ---- x fused cast + transpose
        int xid = bid - 512;
        int nt = xid & 15;
        int cit = (xid >> 4) & 7;
        int b = xid >> 7;
        int n0 = nt * 64, ci0 = cit * 64;
        const float* src = (ci0 < 256) ? (x1 + ((size_t)(b * 256 + ci0)) * 1024)
                                       : (x2 + ((size_t)(b * 256 + ci0 - 256)) * 1024);
        u16* xqb = xq + ((size_t)(b * 512 + ci0)) * 1024;
        u16* lt = (u16*)shm;
#pragma unroll
        for (int p4 = 0; p4 < 4; ++p4) {
            int ch = (t >> 4) + p4 * 16;
            int px = (t & 15) * 4;
            float4 v = *(const float4*)&src[(size_t)ch * 1024 + n0 + px];
            u16x4 pk = {f2bf(v.x), f2bf(v.y), f2bf(v.z), f2bf(v.w)};
            *(u16x4*)&xqb[(size_t)ch * 1024 + n0 + px] = pk;
            lt[(px + 0) * 65 + ch] = pk[0];
            lt[(px + 1) * 65 + ch] = pk[1];
            lt[(px + 2) * 65 + ch] = pk[2];
            lt[(px + 3) * 65 + ch] = pk[3];
        }
        __syncthreads();
        {
            int px_l = t >> 2, c16 = (t & 3) * 16;
            int n = n0 + px_l;
            int y = n >> 5, x = n & 31;
            int p = (y + 1) * 34 + (x + 1);
            u16* dst = xT + ((size_t)b * 1156 + p) * 512 + ci0 + c16;
            *(s16x8*)&dst[0] = *(const s16x8*)&lt[px_l * 65 + c16];
            *(s16x8*)&dst[8] = *(const s16x8*)&lt[px_l * 65 + c16 + 8];
        }
    } else if (bid < 2576) {                // ---- border zero
        int b = bid - 2560;
        u16* base = xT + (size_t)b * 1156 * 512;
        s16x8 z = {0, 0, 0, 0, 0, 0, 0, 0};
        for (int idx = t; idx < 132 * 64; idx += 256) {
            int row = idx >> 6, seg = idx & 63;
            int p;
            if (row < 34) p = row;
            else if (row < 68) p = 1122 + (row - 34);
            else if (row < 100) p = (row - 67) * 34;
            else p = (row - 99) * 34 + 33;
            *(s16x8*)&base[(size_t)p * 512 + seg * 8] = z;
        }
    } else if (bid < 3600) {                // ---- rm
        int idx = (bid - 2576) * 256 + t;
        int c = idx >> 9, d = idx & 511;
        float s = 0.f;
#pragma unroll
        for (int k = 0; k < 16; ++k) s = fmaf(w1[c * 16 + k], w2[d * 16 + k], s);
        rm[idx] = s;
    } else {                                // ---- wwb cast
        int idx = (bid - 3600) * 256 + t;
        float4 v = ((const float4*)ww)[idx];
        u16x4 pk = {f2bf(v.x), f2bf(v.y), f2bf(v.z), f2bf(v.w)};
        *(u16x4*)&wwb[(size_t)idx * 4] = pk;
    }
}

// ================================================================ SIM GEMM (R6-proven)
// simT[b][d][c] = bf16( (xq[c]·xq[d]) * scale + rm[c][d] )   (128x128 tile, BK=64)
__global__ __launch_bounds__(256) void sim_gemm(const u16* __restrict__ xq,
                                                const float* __restrict__ rm,
                                                u16* __restrict__ simT) {
    __shared__ __attribute__((aligned(16))) u16 smem[128 * 128];
    u16* As = smem;
    u16* Bs = smem + 128 * 64;
    const int b = blockIdx.z, m0 = blockIdx.y * 128, n0 = blockIdx.x * 128;
    const int t = threadIdx.x, w = t >> 6, l = t & 63;
    const u16* xb = xq + (size_t)b * 512 * 1024;

    const u16 *agp[4], *bgp[4];
    u16 *ald[4], *bld[4];
#pragma unroll
    for (int i = 0; i < 4; ++i) {
        int rr = w * 8 + i * 32 + (l >> 3);
        int gi = (l & 7) ^ (rr & 7);
        agp[i] = xb + (size_t)(m0 + rr) * 1024 + gi * 8;
        bgp[i] = xb + (size_t)(n0 + rr) * 1024 + gi * 8;
        ald[i] = &As[(w * 8 + i * 32) * 64];
        bld[i] = &Bs[(w * 8 + i * 32) * 64];
    }

    f32x4 acc[4][4] = {};
    const int wm = (w >> 1) * 64, wn = (w & 1) * 64;

    for (int kt = 0; kt < 16; ++kt) {
        int ko = kt << 6;
        if (kt) __syncthreads();
#pragma unroll
        for (int i = 0; i < 4; ++i) gload_lds16(agp[i] + ko, ald[i]);
#pragma unroll
        for (int i = 0; i < 4; ++i) gload_lds16(bgp[i] + ko, bld[i]);
        __syncthreads();
#pragma unroll
        for (int kk = 0; kk < 2; ++kk) {
            int gbase = kk * 4 + (l >> 4);
            s16x8 af[4], bf[4];
#pragma unroll
            for (int i = 0; i < 4; ++i) {
                int row = wm + i * 16 + (l & 15);
                af[i] = *(const s16x8*)&As[row * 64 + ((gbase ^ (row & 7)) << 3)];
            }
#pragma unroll
            for (int j = 0; j < 4; ++j) {
                int row = wn + j * 16 + (l & 15);
                bf[j] = *(const s16x8*)&Bs[row * 64 + ((gbase ^ (row & 7)) << 3)];
            }
#pragma unroll
            for (int i = 0; i < 4; ++i)
#pragma unroll
                for (int j = 0; j < 4; ++j)
                    acc[i][j] = __builtin_amdgcn_mfma_f32_16x16x32_bf16(af[i], bf[j], acc[i][j], 0, 0, 0);
        }
    }

    // epilogue: bias + transposed bf16 store (in-LDS transpose)
    __syncthreads();
    const int col = l & 15, r4 = (l >> 4) * 4;
    const float scale = 0.04419417382415922f;   // 512^-0.5
#pragma unroll
    for (int i = 0; i < 4; ++i)
#pragma unroll
        for (int j = 0; j < 4; ++j) {
            int n_l = wn + j * 16 + col;        // d within tile
            int m_b = wm + i * 16 + r4;         // c chunk base
            u16x4 pk;
#pragma unroll
            for (int reg = 0; reg < 4; ++reg) {
                float v = acc[i][j][reg] * scale
                        + rm[(size_t)(m0 + m_b + reg) * 512 + (n0 + n_l)];
                pk[reg] = f2bf(v);
            }
            *(u16x4*)&smem[n_l * 128 + (m_b ^ ((n_l & 15) << 3))] = pk;
        }
    __syncthreads();
    u16* sTb = simT + (size_t)b * 512 * 512;
    {
        int n_l = t >> 1;
#pragma unroll
        for (int rep = 0; rep < 8; ++rep) {
            int c0 = (((t & 1) + rep * 2) << 3);
            s16x8 v = *(const s16x8*)&smem[n_l * 128 + (c0 ^ ((n_l & 15) << 3))];
            *(s16x8*)&sTb[(size_t)(n0 + n_l) * 512 + m0 + c0] = v;
        }
    }
}

// ================================================================ column softmax (R6-proven)
__global__ __launch_bounds__(256) void softmax_t(const u16* __restrict__ simT,
                                                 u16* __restrict__ attnT) {
    __shared__ float scr[256];
    const int t = threadIdx.x;
    const int b = blockIdx.x >> 4, c0 = (blockIdx.x & 15) * 32;
    const int cl = t & 31, g = t >> 5;
    const u16* sp = simT + (size_t)b * 512 * 512 + c0 + cl;
    u16* ap = attnT + (size_t)b * 512 * 512 + c0 + cl;

    float s = 0.f;
#pragma unroll 8
    for (int dd = 0; dd < 64; ++dd) {
        int d = g * 64 + dd;
        s += __expf(bf2f(sp[(size_t)d * 512]));
    }
    scr[t] = s;
    __syncthreads();
    float tot = 0.f;
#pragma unroll
    for (int k = 0; k < 8; ++k) tot += scr[k * 32 + cl];
    float inv = 1.f / tot;
#pragma unroll 8
    for (int dd = 0; dd < 64; ++dd) {
        int d = g * 64 + dd;
        float e = __expf(bf2f(sp[(size_t)d * 512])) * inv;
        ap[(size_t)d * 512] = f2bf(e);
    }
}

// ================================================================ conv implicit GEMM (R3..R6-proven)
__global__ __launch_bounds__(256) void conv_gemm(const u16* __restrict__ wA,
                                                 const u16* __restrict__ xT,
                                                 u16* __restrict__ vT) {
    __shared__ __attribute__((aligned(16))) u16 smem[128 * 128];
    u16* As = smem;
    u16* Bs = smem + 128 * 64;
    const int b = blockIdx.z, m0 = blockIdx.y * 128, n0 = blockIdx.x * 128;
    const int t = threadIdx.x, w = t >> 6, l = t & 63;
    const u16* xTb = xT + (size_t)b * 1156 * 512;

    int gi[4], pb[4];
    const u16* agp[4];
    u16 *ald[4], *bld[4];
#pragma unroll
    for (int i = 0; i < 4; ++i) {
        int rr = w * 8 + i * 32 + (l >> 3);
        gi[i] = (l & 7) ^ (rr & 7);
        agp[i] = wA + (size_t)(m0 + rr) * 4608 + gi[i] * 8;
        int n = n0 + rr;
        pb[i] = (n >> 5) * 34 + (n & 31);
        ald[i] = &As[(w * 8 + i * 32) * 64];
        bld[i] = &Bs[(w * 8 + i * 32) * 64];
    }

    f32x4 acc[4][4] = {};
    const int wm = (w >> 1) * 64, wn = (w & 1) * 64;

    for (int kt = 0; kt < 72; ++kt) {
        int r = kt >> 3, ci0k = (kt & 7) << 6;
        int rdiv3 = (r * 11) >> 5;
        int poff = rdiv3 * 34 + (r - rdiv3 * 3);
        int aofs = r * 512 + ci0k;
        if (kt) __syncthreads();
#pragma unroll
        for (int i = 0; i < 4; ++i) gload_lds16(agp[i] + aofs, ald[i]);
#pragma unroll
        for (int i = 0; i < 4; ++i)
            gload_lds16(xTb + (size_t)(pb[i] + poff) * 512 + ci0k + gi[i] * 8, bld[i]);
        __syncthreads();

#pragma unroll
        for (int kk = 0; kk < 2; ++kk) {
            int gbase = kk * 4 + (l >> 4);
            s16x8 af[4], bf[4];
#pragma unroll
            for (int i = 0; i < 4; ++i) {
                int row = wm + i * 16 + (l & 15);
                af[i] = *(const s16x8*)&As[row * 64 + ((gbase ^ (row & 7)) << 3)];
            }
#pragma unroll
            for (int j = 0; j < 4; ++j) {
                int row = wn + j * 16 + (l & 15);
                bf[j] = *(const s16x8*)&Bs[row * 64 + ((gbase ^ (row & 7)) << 3)];
            }
#pragma unroll
            for (int i = 0; i < 4; ++i)
#pragma unroll
                for (int j = 0; j < 4; ++j)
                    acc[i][j] = __builtin_amdgcn_mfma_f32_16x16x32_bf16(af[i], bf[j], acc[i][j], 0, 0, 0);
        }
    }

    __syncthreads();
    const int col = l & 15, r4 = (l >> 4) * 4;
#pragma unroll
    for (int i = 0; i < 4; ++i)
#pragma unroll
        for (int j = 0; j < 4; ++j) {
            int n_l = wn + j * 16 + col;
            int co_b = wm + i * 16 + r4;
            u16x4 pk = {f2bf(acc[i][j][0]), f2bf(acc[i][j][1]),
                        f2bf(acc[i][j][2]), f2bf(acc[i][j][3])};
            *(u16x4*)&smem[n_l * 128 + (co_b ^ ((n_l & 15) << 3))] = pk;
        }
    __syncthreads();
    u16* vTb = vT + (size_t)b * 1024 * 512;
    {
        int n_l = t >> 1;
#pragma unroll
        for (int rep = 0; rep < 8; ++rep) {
            int c0 = (((t & 1) + rep * 2) << 3);
            s16x8 v = *(const s16x8*)&smem[n_l * 128 + (c0 ^ ((n_l & 15) << 3))];
            *(s16x8*)&vTb[(size_t)(n0 + n_l) * 512 + m0 + c0] = v;
        }
    }
}

// ================================================================ generic bf16 MFMA NT GEMM (R3..R6-proven)
// MODE 1: bf16 out (wattn); MODE 2: f32 out (final)
template <int MODE>
__global__ __launch_bounds__(256) void gemm_nt(const u16* __restrict__ A, size_t sA,
                                               const u16* __restrict__ B, size_t sB,
                                               void* __restrict__ Cv, size_t sC,
                                               int K, int ldc) {
    __shared__ __attribute__((aligned(16))) u16 As[128 * 64];
    __shared__ __attribute__((aligned(16))) u16 Bs[128 * 64];
    const int b = blockIdx.z, m0 = blockIdx.y * 128, n0 = blockIdx.x * 128;
    const int t = threadIdx.x, w = t >> 6, l = t & 63;
    const u16* Ab = A + (size_t)b * sA;
    const u16* Bb = B + (size_t)b * sB;

    const u16 *agp[4], *bgp[4];
    u16 *ald[4], *bld[4];
#pragma unroll
    for (int i = 0; i < 4; ++i) {
        int rr = w * 8 + i * 32 + (l >> 3);
        int gi = (l & 7) ^ (rr & 7);
        agp[i] = Ab + (size_t)(m0 + rr) * K + gi * 8;
        bgp[i] = Bb + (size_t)(n0 + rr) * K + gi * 8;
        ald[i] = &As[(w * 8 + i * 32) * 64];
        bld[i] = &Bs[(w * 8 + i * 32) * 64];
    }

    f32x4 acc[4][4] = {};
    const int wm = (w >> 1) * 64, wn = (w & 1) * 64;
    const int nkt = K >> 6;
    for (int kt = 0; kt < nkt; ++kt) {
        int ko = kt << 6;
        if (kt) __syncthreads();
#pragma unroll
        for (int i = 0; i < 4; ++i) gload_lds16(agp[i] + ko, ald[i]);
#pragma unroll
        for (int i = 0; i < 4; ++i) gload_lds16(bgp[i] + ko, bld[i]);
        __syncthreads();
#pragma unroll
        for (int kk = 0; kk < 2; ++kk) {
            int gbase = kk * 4 + (l >> 4);
            s16x8 af[4], bf[4];
#pragma unroll
            for (int i = 0; i < 4; ++i) {
                int row = wm + i * 16 + (l & 15);
                af[i] = *(const s16x8*)&As[row * 64 + ((gbase ^ (row & 7)) << 3)];
            }
#pragma unroll
            for (int j = 0; j < 4; ++j) {
                int row = wn + j * 16 + (l & 15);
                bf[j] = *(const s16x8*)&Bs[row * 64 + ((gbase ^ (row & 7)) << 3)];
            }
#pragma unroll
            for (int i = 0; i < 4; ++i)
#pragma unroll
                for (int j = 0; j < 4; ++j)
                    acc[i][j] = __builtin_amdgcn_mfma_f32_16x16x32_bf16(af[i], bf[j], acc[i][j], 0, 0, 0);
        }
    }

    const int col = l & 15, r4 = (l >> 4) * 4;
#pragma unroll
    for (int i = 0; i < 4; ++i)
#pragma unroll
        for (int j = 0; j < 4; ++j)
#pragma unroll
            for (int reg = 0; reg < 4; ++reg) {
                int m = m0 + wm + i * 16 + r4 + reg;
                int n = n0 + wn + j * 16 + col;
                if (MODE == 1) {
                    u16* C = (u16*)Cv + (size_t)b * sC;
                    C[(size_t)m * ldc + n] = f2bf(acc[i][j][reg]);
                } else {
                    float* C = (float*)Cv + (size_t)b * sC;
                    C[(size_t)m * ldc + n] = acc[i][j][reg];
                }
            }
}

// ----------------------------------------------------------------
extern "C" void kernel_launch(void* const* d_in, const int* in_sizes, int n_in,
                              void* d_out, int out_size, void* d_ws, size_t ws_size,
                              hipStream_t stream) {
    (void)in_sizes; (void)n_in; (void)out_size; (void)ws_size;
    const float* x1 = (const float*)d_in[0];
    const float* x2 = (const float*)d_in[1];
    const float* gw = (const float*)d_in[2];
    const float* ww = (const float*)d_in[3];
    const float* w1 = (const float*)d_in[4];
    const float* w2 = (const float*)d_in[5];
    float* out = (float*)d_out;
    float* ws = (float*)d_ws;

    u16* xT    = (u16*)(ws + OFF_XT);
    u16* xq    = (u16*)(ws + OFF_XQ);
    u16* vT    = (u16*)(ws + OFF_XQ);      // after xq dies (sim_gemm done)
    u16* attnT = (u16*)(ws + OFF_ATTNT);   // own region (de-aliased)
    u16* simT  = (u16*)(ws + OFF_SIMT);
    u16* wattn = (u16*)(ws + OFF_SIMT);    // after simT dies (softmax_t done)
    u16* wA    = (u16*)(ws + OFF_WA);
    float* rm  = ws + OFF_RM;
    u16* wwb   = (u16*)(ws + OFF_WWB);

    prep_kernel<<<3728, 256, 0, stream>>>(x1, x2, gw, ww, w1, w2, rm, wA, wwb, xT, xq);
    // simT[b][d][c] = bf16(xq_c . xq_d * scale + rm[c][d])
    sim_gemm<<<dim3(4, 4, 16), 256, 0, stream>>>(xq, rm, simT);
    softmax_t<<<256, 256, 0, stream>>>(simT, attnT);
    // wattn[b][o][d] = sum_c wwb[o][c] * attnT[b][d][c]  (bf16 out)
    gemm_nt<1><<<dim3(4, 2, 16), 256, 0, stream>>>(
        wwb, 0, attnT, (size_t)512 * 512, wattn, (size_t)256 * 512, 512, 512);
    conv_gemm<<<dim3(8, 4, 16), 256, 0, stream>>>(wA, xT, vT);
    // out[b][o][n] = sum_d wattn[b][o][d] * vT[b][n][d]  (f32 out)
    gemm_nt<2><<<dim3(8, 2, 16), 256, 0, stream>>>(
        wattn, (size_t)256 * 512, vT, (size_t)1024 * 512, out, (size_t)256 * 1024, 512, 1024);
}

// Round 9
// 229.860 us; speedup vs baseline: 1.0179x; 1.0179x over previous
//
#include <hip/hip_runtime.h>
#include <math.h>

typedef float f32x4 __attribute__((ext_vector_type(4)));
typedef short s16x8 __attribute__((ext_vector_type(8)));
typedef unsigned int u32;
typedef unsigned short u16;
typedef u16 u16x4 __attribute__((ext_vector_type(4)));

// ---------------- ws layout (float offsets), 58.5 MB peak (== R8 proven) ----
// XQ region [4734976,8929280): xq bf16 (prep..sim_part) -> attnT bf16 at
//   4734976 (finish..gemm1) + wattn bf16 at 6832128 (gemm1..gemm2)
// P region [8929280,13123584): p0/p1 bf16 sim partials (sim_part..finish)
//   -> vT bf16 whole region (conv..gemm2)
static constexpr size_t OFF_XT    = 0;          // bf16 [16,1156,512]
static constexpr size_t OFF_XQ    = 4734976;
static constexpr size_t OFF_ATTNT = 4734976;    // after xq dies
static constexpr size_t OFF_WATTN = 6832128;
static constexpr size_t OFF_P0    = 8929280;    // bf16 [16,512,512]
static constexpr size_t OFF_P1    = 11026432;   // bf16 [16,512,512]
static constexpr size_t OFF_VT    = 8929280;    // after p0/p1 die
static constexpr size_t OFF_WA    = 13123584;   // bf16 [512,4608]
static constexpr size_t OFF_RM    = 14303232;   // f32 [512,512]
static constexpr size_t OFF_WWB   = 14565376;   // bf16 [256,512]
// end 14,630,912 fl = 58.5 MB

__device__ __forceinline__ u16 f2bf(float f) {
    u32 u = __float_as_uint(f);
    u32 r = (u + 0x7FFFu + ((u >> 16) & 1u)) >> 16;   // RNE
    return (u16)r;
}
__device__ __forceinline__ float bf2f(u16 v) {
    return __uint_as_float(((u32)v) << 16);
}

__device__ __forceinline__ void gload_lds16(const void* g, void* l) {
    __builtin_amdgcn_global_load_lds(
        (const u32 __attribute__((address_space(1)))*)(uintptr_t)g,
        (u32 __attribute__((address_space(3)))*)(uintptr_t)l, 16, 0, 0);
}

// ================================================================ PREP (R6/R8-proven)
__global__ __launch_bounds__(256) void prep_kernel(const float* __restrict__ x1,
                                                   const float* __restrict__ x2,
                                                   const float* __restrict__ gw,
                                                   const float* __restrict__ ww,
                                                   const float* __restrict__ w1,
                                                   const float* __restrict__ w2,
                                                   float* __restrict__ rm,
                                                   u16* __restrict__ wA,
                                                   u16* __restrict__ wwb,
                                                   u16* __restrict__ xT,
                                                   u16* __restrict__ xq) {
    __shared__ __attribute__((aligned(16))) u32 shm[4608];
    const int t = threadIdx.x;
    const int bid = blockIdx.x;

    if (bid < 512) {                        // ---- gw permute-cast
        const int co = bid;
        const float* g = gw + (size_t)co * 4608;
        float* lf = (float*)shm;
#pragma unroll
        for (int i = 0; i < 18; ++i) lf[t + i * 256] = g[t + i * 256];
        __syncthreads();
        u16* dst = wA + (size_t)co * 4608;
#pragma unroll
        for (int i = 0; i < 18; ++i) {
            int k = t + i * 256;
            int r = k >> 9, ci = k & 511;
            dst[k] = f2bf(lf[ci * 9 + r]);
        }
    } else if (bid < 2560) {                // ---- x fused cast + transpose
        int xid = bid - 512;
        int nt = xid & 15;
        int cit = (xid >> 4) & 7;
        int b = xid >> 7;
        int n0 = nt * 64, ci0 = cit * 64;
        const float* src = (ci0 < 256) ? (x1 + ((size_t)(b * 256 + ci0)) * 1024)
                                       : (x2 + ((size_t)(b * 256 + ci0 - 256)) * 1024);
        u16* xqb = xq + ((size_t)(b * 512 + ci0)) * 1024;
        u16* lt = (u16*)shm;
#pragma unroll
        for (int p4 = 0; p4 < 4; ++p4) {
            int ch = (t >> 4) + p4 * 16;
            int px = (t & 15) * 4;
            float4 v = *(const float4*)&src[(size_t)ch * 1024 + n0 + px];
            u16x4 pk = {f2bf(v.x), f2bf(v.y), f2bf(v.z), f2bf(v.w)};
            *(u16x4*)&xqb[(size_t)ch * 1024 + n0 + px] = pk;
            lt[(px + 0) * 65 + ch] = pk[0];
            lt[(px + 1) * 65 + ch] = pk[1];
            lt[(px + 2) * 65 + ch] = pk[2];
            lt[(px + 3) * 65 + ch] = pk[3];
        }
        __syncthreads();
        {
            int px_l = t >> 2, c16 = (t & 3) * 16;
            int n = n0 + px_l;
            int y = n >> 5, x = n & 31;
            int p = (y + 1) * 34 + (x + 1);
            u16* dst = xT + ((size_t)b * 1156 + p) * 512 + ci0 + c16;
            *(s16x8*)&dst[0] = *(const s16x8*)&lt[px_l * 65 + c16];
            *(s16x8*)&dst[8] = *(const s16x8*)&lt[px_l * 65 + c16 + 8];
        }
    } else if (bid < 2576) {                // ---- border zero
        int b = bid - 2560;
        u16* base = xT + (size_t)b * 1156 * 512;
        s16x8 z = {0, 0, 0, 0, 0, 0, 0, 0};
        for (int idx = t; idx < 132 * 64; idx += 256) {
            int row = idx >> 6, seg = idx & 63;
            int p;
            if (row < 34) p = row;
            else if (row < 68) p = 1122 + (row - 34);
            else if (row < 100) p = (row - 67) * 34;
            else p = (row - 99) * 34 + 33;
            *(s16x8*)&base[(size_t)p * 512 + seg * 8] = z;
        }
    } else if (bid < 3600) {                // ---- rm
        int idx = (bid - 2576) * 256 + t;
        int c = idx >> 9, d = idx & 511;
        float s = 0.f;
#pragma unroll
        for (int k = 0; k < 16; ++k) s = fmaf(w1[c * 16 + k], w2[d * 16 + k], s);
        rm[idx] = s;
    } else {                                // ---- wwb cast
        int idx = (bid - 3600) * 256 + t;
        float4 v = ((const float4*)ww)[idx];
        u16x4 pk = {f2bf(v.x), f2bf(v.y), f2bf(v.z), f2bf(v.w)};
        *(u16x4*)&wwb[(size_t)idx * 4] = pk;
    }
}

// ================================================================ SIM partial GEMM (split-K)
// pK[b][d][c] = bf16( sum_{k in half} xq[c][k]*xq[d][k] )   128x128 tile, BK=64
// grid (8,4,16): x&3 = d-tile, x>>2 = khalf, y = c-tile, z = b.  512 blocks (2/CU).
__global__ __launch_bounds__(256) void sim_part(const u16* __restrict__ xq,
                                                u16* __restrict__ simP) {
    __shared__ __attribute__((aligned(16))) u16 smem[128 * 128];
    u16* As = smem;
    u16* Bs = smem + 128 * 64;
    const int b = blockIdx.z, m0 = blockIdx.y * 128;
    const int n0 = (blockIdx.x & 3) * 128, khalf = blockIdx.x >> 2;
    const int t = threadIdx.x, w = t >> 6, l = t & 63;
    const u16* xb = xq + (size_t)b * 512 * 1024 + khalf * 512;

    const u16 *agp[4], *bgp[4];
    u16 *ald[4], *bld[4];
#pragma unroll
    for (int i = 0; i < 4; ++i) {
        int rr = w * 8 + i * 32 + (l >> 3);
        int gi = (l & 7) ^ (rr & 7);
        agp[i] = xb + (size_t)(m0 + rr) * 1024 + gi * 8;
        bgp[i] = xb + (size_t)(n0 + rr) * 1024 + gi * 8;
        ald[i] = &As[(w * 8 + i * 32) * 64];
        bld[i] = &Bs[(w * 8 + i * 32) * 64];
    }

    f32x4 acc[4][4] = {};
    const int wm = (w >> 1) * 64, wn = (w & 1) * 64;

    for (int kt = 0; kt < 8; ++kt) {
        int ko = kt << 6;
        if (kt) __syncthreads();
#pragma unroll
        for (int i = 0; i < 4; ++i) gload_lds16(agp[i] + ko, ald[i]);
#pragma unroll
        for (int i = 0; i < 4; ++i) gload_lds16(bgp[i] + ko, bld[i]);
        __syncthreads();
#pragma unroll
        for (int kk = 0; kk < 2; ++kk) {
            int gbase = kk * 4 + (l >> 4);
            s16x8 af[4], bf[4];
#pragma unroll
            for (int i = 0; i < 4; ++i) {
                int row = wm + i * 16 + (l & 15);
                af[i] = *(const s16x8*)&As[row * 64 + ((gbase ^ (row & 7)) << 3)];
            }
#pragma unroll
            for (int j = 0; j < 4; ++j) {
                int row = wn + j * 16 + (l & 15);
                bf[j] = *(const s16x8*)&Bs[row * 64 + ((gbase ^ (row & 7)) << 3)];
            }
#pragma unroll
            for (int i = 0; i < 4; ++i)
#pragma unroll
                for (int j = 0; j < 4; ++j)
                    acc[i][j] = __builtin_amdgcn_mfma_f32_16x16x32_bf16(af[i], bf[j], acc[i][j], 0, 0, 0);
        }
    }

    // transposed bf16 store [d][c] (proven epilogue, no bias here)
    __syncthreads();
    const int col = l & 15, r4 = (l >> 4) * 4;
#pragma unroll
    for (int i = 0; i < 4; ++i)
#pragma unroll
        for (int j = 0; j < 4; ++j) {
            int n_l = wn + j * 16 + col;
            int m_b = wm + i * 16 + r4;
            u16x4 pk = {f2bf(acc[i][j][0]), f2bf(acc[i][j][1]),
                        f2bf(acc[i][j][2]), f2bf(acc[i][j][3])};
            *(u16x4*)&smem[n_l * 128 + (m_b ^ ((n_l & 15) << 3))] = pk;
        }
    __syncthreads();
    u16* sTb = simP + (size_t)khalf * 4194304 + (size_t)b * 512 * 512;
    {
        int n_l = t >> 1;
#pragma unroll
        for (int rep = 0; rep < 8; ++rep) {
            int c0 = (((t & 1) + rep * 2) << 3);
            s16x8 v = *(const s16x8*)&smem[n_l * 128 + (c0 ^ ((n_l & 15) << 3))];
            *(s16x8*)&sTb[(size_t)(n0 + n_l) * 512 + m0 + c0] = v;
        }
    }
}

// ================================================================ FINISH (softmax_t pattern)
// attnT[b][d][c] = softmax_d( (p0+p1)*scale + rm[c][d] ) over d, written [d][c]
// grid 256: b = bid>>4, c0 = (bid&15)*32.  lane cl = t&31 -> c, group g = t>>5 (64 d each)
__global__ __launch_bounds__(256) void finish_kernel(const u16* __restrict__ p0,
                                                     const u16* __restrict__ p1,
                                                     const float* __restrict__ rm,
                                                     u16* __restrict__ attnT) {
    __shared__ float rml[32 * 513];   // rm rows c0..c0+31, stride 513 (conflict-free)
    __shared__ float scr[256];
    const int t = threadIdx.x;
    const int b = blockIdx.x >> 4, c0 = (blockIdx.x & 15) * 32;
    const int cl = t & 31, g = t >> 5;
    const float scale = 0.04419417382415922f;   // 512^-0.5

    for (int idx = t; idx < 32 * 512; idx += 256) {
        int c_l = idx >> 9, d = idx & 511;
        rml[c_l * 513 + d] = rm[(size_t)(c0 + c_l) * 512 + d];
    }
    __syncthreads();

    const u16* q0 = p0 + (size_t)b * 262144 + c0 + cl;
    const u16* q1 = p1 + (size_t)b * 262144 + c0 + cl;
    u16* ap = attnT + (size_t)b * 262144 + c0 + cl;
    const float* rp = &rml[cl * 513];

    float s = 0.f;
#pragma unroll 8
    for (int dd = 0; dd < 64; ++dd) {
        int d = g * 64 + dd;
        float v = (bf2f(q0[(size_t)d * 512]) + bf2f(q1[(size_t)d * 512])) * scale + rp[d];
        float e = __expf(v);
        s += e;
        ap[(size_t)d * 512] = f2bf(e);   // unnormalized, rescaled in phase 2
    }
    scr[t] = s;
    __syncthreads();
    float tot = 0.f;
#pragma unroll
    for (int k = 0; k < 8; ++k) tot += scr[k * 32 + cl];
    float inv = 1.f / tot;
#pragma unroll 8
    for (int dd = 0; dd < 64; ++dd) {
        int d = g * 64 + dd;
        ap[(size_t)d * 512] = f2bf(bf2f(ap[(size_t)d * 512]) * inv);
    }
}

// ================================================================ conv implicit GEMM (R3..R8-proven)
__global__ __launch_bounds__(256) void conv_gemm(const u16* __restrict__ wA,
                                                 const u16* __restrict__ xT,
                                                 u16* __restrict__ vT) {
    __shared__ __attribute__((aligned(16))) u16 smem[128 * 128];
    u16* As = smem;
    u16* Bs = smem + 128 * 64;
    const int b = blockIdx.z, m0 = blockIdx.y * 128, n0 = blockIdx.x * 128;
    const int t = threadIdx.x, w = t >> 6, l = t & 63;
    const u16* xTb = xT + (size_t)b * 1156 * 512;

    int gi[4], pb[4];
    const u16* agp[4];
    u16 *ald[4], *bld[4];
#pragma unroll
    for (int i = 0; i < 4; ++i) {
        int rr = w * 8 + i * 32 + (l >> 3);
        gi[i] = (l & 7) ^ (rr & 7);
        agp[i] = wA + (size_t)(m0 + rr) * 4608 + gi[i] * 8;
        int n = n0 + rr;
        pb[i] = (n >> 5) * 34 + (n & 31);
        ald[i] = &As[(w * 8 + i * 32) * 64];
        bld[i] = &Bs[(w * 8 + i * 32) * 64];
    }

    f32x4 acc[4][4] = {};
    const int wm = (w >> 1) * 64, wn = (w & 1) * 64;

    for (int kt = 0; kt < 72; ++kt) {
        int r = kt >> 3, ci0k = (kt & 7) << 6;
        int rdiv3 = (r * 11) >> 5;
        int poff = rdiv3 * 34 + (r - rdiv3 * 3);
        int aofs = r * 512 + ci0k;
        if (kt) __syncthreads();
#pragma unroll
        for (int i = 0; i < 4; ++i) gload_lds16(agp[i] + aofs, ald[i]);
#pragma unroll
        for (int i = 0; i < 4; ++i)
            gload_lds16(xTb + (size_t)(pb[i] + poff) * 512 + ci0k + gi[i] * 8, bld[i]);
        __syncthreads();

#pragma unroll
        for (int kk = 0; kk < 2; ++kk) {
            int gbase = kk * 4 + (l >> 4);
            s16x8 af[4], bf[4];
#pragma unroll
            for (int i = 0; i < 4; ++i) {
                int row = wm + i * 16 + (l & 15);
                af[i] = *(const s16x8*)&As[row * 64 + ((gbase ^ (row & 7)) << 3)];
            }
#pragma unroll
            for (int j = 0; j < 4; ++j) {
                int row = wn + j * 16 + (l & 15);
                bf[j] = *(const s16x8*)&Bs[row * 64 + ((gbase ^ (row & 7)) << 3)];
            }
#pragma unroll
            for (int i = 0; i < 4; ++i)
#pragma unroll
                for (int j = 0; j < 4; ++j)
                    acc[i][j] = __builtin_amdgcn_mfma_f32_16x16x32_bf16(af[i], bf[j], acc[i][j], 0, 0, 0);
        }
    }

    __syncthreads();
    const int col = l & 15, r4 = (l >> 4) * 4;
#pragma unroll
    for (int i = 0; i < 4; ++i)
#pragma unroll
        for (int j = 0; j < 4; ++j) {
            int n_l = wn + j * 16 + col;
            int co_b = wm + i * 16 + r4;
            u16x4 pk = {f2bf(acc[i][j][0]), f2bf(acc[i][j][1]),
                        f2bf(acc[i][j][2]), f2bf(acc[i][j][3])};
            *(u16x4*)&smem[n_l * 128 + (co_b ^ ((n_l & 15) << 3))] = pk;
        }
    __syncthreads();
    u16* vTb = vT + (size_t)b * 1024 * 512;
    {
        int n_l = t >> 1;
#pragma unroll
        for (int rep = 0; rep < 8; ++rep) {
            int c0 = (((t & 1) + rep * 2) << 3);
            s16x8 v = *(const s16x8*)&smem[n_l * 128 + (c0 ^ ((n_l & 15) << 3))];
            *(s16x8*)&vTb[(size_t)(n0 + n_l) * 512 + m0 + c0] = v;
        }
    }
}

// ================================================================ generic bf16 MFMA NT GEMM (proven)
// MODE 1: bf16 out (wattn); MODE 2: f32 out (final)
template <int MODE>
__global__ __launch_bounds__(256) void gemm_nt(const u16* __restrict__ A, size_t sA,
                                               const u16* __restrict__ B, size_t sB,
                                               void* __restrict__ Cv, size_t sC,
                                               int K, int ldc) {
    __shared__ __attribute__((aligned(16))) u16 As[128 * 64];
    __shared__ __attribute__((aligned(16))) u16 Bs[128 * 64];
    const int b = blockIdx.z, m0 = blockIdx.y * 128, n0 = blockIdx.x * 128;
    const int t = threadIdx.x, w = t >> 6, l = t & 63;
    const u16* Ab = A + (size_t)b * sA;
    const u16* Bb = B + (size_t)b * sB;

    const u16 *agp[4], *bgp[4];
    u16 *ald[4], *bld[4];
#pragma unroll
    for (int i = 0; i < 4; ++i) {
        int rr = w * 8 + i * 32 + (l >> 3);
        int gi = (l & 7) ^ (rr & 7);
        agp[i] = Ab + (size_t)(m0 + rr) * K + gi * 8;
        bgp[i] = Bb + (size_t)(n0 + rr) * K + gi * 8;
        ald[i] = &As[(w * 8 + i * 32) * 64];
        bld[i] = &Bs[(w * 8 + i * 32) * 64];
    }

    f32x4 acc[4][4] = {};
    const int wm = (w >> 1) * 64, wn = (w & 1) * 64;
    const int nkt = K >> 6;
    for (int kt = 0; kt < nkt; ++kt) {
        int ko = kt << 6;
        if (kt) __syncthreads();
#pragma unroll
        for (int i = 0; i < 4; ++i) gload_lds16(agp[i] + ko, ald[i]);
#pragma unroll
        for (int i = 0; i < 4; ++i) gload_lds16(bgp[i] + ko, bld[i]);
        __syncthreads();
#pragma unroll
        for (int kk = 0; kk < 2; ++kk) {
            int gbase = kk * 4 + (l >> 4);
            s16x8 af[4], bf[4];
#pragma unroll
            for (int i = 0; i < 4; ++i) {
                int row = wm + i * 16 + (l & 15);
                af[i] = *(const s16x8*)&As[row * 64 + ((gbase ^ (row & 7)) << 3)];
            }
#pragma unroll
            for (int j = 0; j < 4; ++j) {
                int row = wn + j * 16 + (l & 15);
                bf[j] = *(const s16x8*)&Bs[row * 64 + ((gbase ^ (row & 7)) << 3)];
            }
#pragma unroll
            for (int i = 0; i < 4; ++i)
#pragma unroll
                for (int j = 0; j < 4; ++j)
                    acc[i][j] = __builtin_amdgcn_mfma_f32_16x16x32_bf16(af[i], bf[j], acc[i][j], 0, 0, 0);
        }
    }

    const int col = l & 15, r4 = (l >> 4) * 4;
#pragma unroll
    for (int i = 0; i < 4; ++i)
#pragma unroll
        for (int j = 0; j < 4; ++j)
#pragma unroll
            for (int reg = 0; reg < 4; ++reg) {
                int m = m0 + wm + i * 16 + r4 + reg;
                int n = n0 + wn + j * 16 + col;
                if (MODE == 1) {
                    u16* C = (u16*)Cv + (size_t)b * sC;
                    C[(size_t)m * ldc + n] = f2bf(acc[i][j][reg]);
                } else {
                    float* C = (float*)Cv + (size_t)b * sC;
                    C[(size_t)m * ldc + n] = acc[i][j][reg];
                }
            }
}

// ----------------------------------------------------------------
extern "C" void kernel_launch(void* const* d_in, const int* in_sizes, int n_in,
                              void* d_out, int out_size, void* d_ws, size_t ws_size,
                              hipStream_t stream) {
    (void)in_sizes; (void)n_in; (void)out_size; (void)ws_size;
    const float* x1 = (const float*)d_in[0];
    const float* x2 = (const float*)d_in[1];
    const float* gw = (const float*)d_in[2];
    const float* ww = (const float*)d_in[3];
    const float* w1 = (const float*)d_in[4];
    const float* w2 = (const float*)d_in[5];
    float* out = (float*)d_out;
    float* ws = (float*)d_ws;

    u16* xT    = (u16*)(ws + OFF_XT);
    u16* xq    = (u16*)(ws + OFF_XQ);
    u16* attnT = (u16*)(ws + OFF_ATTNT);   // after xq dies
    u16* wattn = (u16*)(ws + OFF_WATTN);
    u16* simP  = (u16*)(ws + OFF_P0);      // p0; p1 at +4,194,304 u16
    u16* p0    = (u16*)(ws + OFF_P0);
    u16* p1    = (u16*)(ws + OFF_P1);
    u16* vT    = (u16*)(ws + OFF_VT);      // after p0/p1 die
    u16* wA    = (u16*)(ws + OFF_WA);
    float* rm  = ws + OFF_RM;
    u16* wwb   = (u16*)(ws + OFF_WWB);

    prep_kernel<<<3728, 256, 0, stream>>>(x1, x2, gw, ww, w1, w2, rm, wA, wwb, xT, xq);
    // p{0,1}[b][d][c] = partial QQ^T halves (512 blocks, 2/CU)
    sim_part<<<dim3(8, 4, 16), 256, 0, stream>>>(xq, simP);
    // attnT[b][d][c] = softmax over d of ((p0+p1)*scale + rm[c][d])
    finish_kernel<<<256, 256, 0, stream>>>(p0, p1, rm, attnT);
    // wattn[b][o][d] = sum_c wwb[o][c] * attnT[b][d][c]  (bf16 out)
    gemm_nt<1><<<dim3(4, 2, 16), 256, 0, stream>>>(
        wwb, 0, attnT, (size_t)512 * 512, wattn, (size_t)256 * 512, 512, 512);
    conv_gemm<<<dim3(8, 4, 16), 256, 0, stream>>>(wA, xT, vT);
    // out[b][o][n] = sum_d wattn[b][o][d] * vT[b][n][d]  (f32 out)
    gemm_nt<2><<<dim3(8, 2, 16), 256, 0, stream>>>(
        wattn, (size_t)256 * 512, vT, (size_t)1024 * 512, out, (size_t)256 * 1024, 512, 1024);
}